// Round 8
// baseline (381.911 us; speedup 1.0000x reference)
//
#include <hip/hip_runtime.h>
#include <hip/hip_bf16.h>
#include <stdint.h>

typedef __attribute__((ext_vector_type(8))) short short8;
typedef __attribute__((ext_vector_type(4))) float f32x4;

#define CH 64
#define NC 128   /* 8192 / CH */

__device__ __forceinline__ unsigned short f2bf(float f) {
  union { float f; unsigned u; } x; x.f = f;
  unsigned u = x.u;
  u = (u + 0x7fffu + ((u >> 16) & 1u)) >> 16;
  return (unsigned short)u;
}
__device__ __forceinline__ float bf2f(unsigned u16) {
  union { unsigned u; float f; } x; x.u = u16 << 16;
  return x.f;
}

#define GLOAD_LDS16(gptr, lptr) \
  __builtin_amdgcn_global_load_lds((const __attribute__((address_space(1))) void*)(gptr), \
                                   (__attribute__((address_space(3))) void*)(lptr), 16, 0, 0)

// ---------------- fused f32 -> bf16 convert for X, W_hg, W_out ----------------
#define NQ_X   4194304  /* 16777216/4 */
#define NQ_WHG  262144  /* 1048576/4  */
#define NQ_WOUT 131072  /* 524288/4   */
__global__ void k_cvt_all(const float* __restrict__ X, const float* __restrict__ Whg,
                          const float* __restrict__ Wout,
                          unsigned short* __restrict__ Xb, unsigned short* __restrict__ Whgb,
                          unsigned short* __restrict__ Woutb) {
  int i = blockIdx.x * blockDim.x + threadIdx.x;  // 0 .. 4587519
  const float* src; unsigned short* dst; int off;
  if (i < NQ_X)                { src = X;    dst = Xb;    off = i; }
  else if (i < NQ_X + NQ_WHG)  { src = Whg;  dst = Whgb;  off = i - NQ_X; }
  else                         { src = Wout; dst = Woutb; off = i - NQ_X - NQ_WHG; }
  float4 f = reinterpret_cast<const float4*>(src)[off];
  ushort4 o = make_ushort4(f2bf(f.x), f2bf(f.y), f2bf(f.z), f2bf(f.w));
  reinterpret_cast<ushort4*>(dst)[off] = o;
}

// ---------------- GEMM1: hg = X @ W_hg^T, dual-B (h and gate halves) ---------
// Epilogue fuses the MinGRU nonlinearity, writes packed (a|v<<16) bf16 pairs,
// AND computes the per-chunk scan aggregates (scanA fused).
// NOTE: __launch_bounds__(256,2) is REQUIRED — acc0+acc1 = 128 regs must fit
// the unified VGPR+AGPR file. (256,3) caps at 170 and spills accumulators to
// scratch: measured +1.3 GB HBM traffic, MfmaUtil 21->7.7%, 2.7x slower (r6).
__global__ __launch_bounds__(256, 2) void k_gemm1(
    const unsigned short* __restrict__ Xb,
    const unsigned short* __restrict__ Wb,
    uint32_t* __restrict__ avArr,
    float* __restrict__ Acar, float* __restrict__ Vcar)
{
  __shared__ unsigned short As[128 * 64];
  __shared__ unsigned short Bs0[128 * 64];
  __shared__ unsigned short Bs1[128 * 64];

  const int m0 = blockIdx.y * 128;
  const int i0 = blockIdx.x * 128;
  const int tid = threadIdx.x;
  const int lane = tid & 63;
  const int wave = tid >> 6;
  const int wm = (wave >> 1) * 64;
  const int wn = (wave & 1) * 64;
  const int srow = tid >> 3;         // 0..31
  const int scol = (tid & 7) * 8;    // element col in [0,64)

  f32x4 acc0[4][4], acc1[4][4];
#pragma unroll
  for (int f = 0; f < 4; ++f)
#pragma unroll
    for (int g = 0; g < 4; ++g) {
      acc0[f][g] = f32x4{0.f, 0.f, 0.f, 0.f};
      acc1[f][g] = f32x4{0.f, 0.f, 0.f, 0.f};
    }

  for (int k0 = 0; k0 < 512; k0 += 64) {
    __syncthreads();   // all waves done reading previous tile
#pragma unroll
    for (int j = 0; j < 4; ++j) {
      int row = j * 32 + srow;
      GLOAD_LDS16(Xb + (size_t)(m0 + row) * 512 + k0 + scol, As + row * 64 + scol);
    }
#pragma unroll
    for (int j = 0; j < 4; ++j) {
      int row = j * 32 + srow;
      GLOAD_LDS16(Wb + (size_t)(i0 + row) * 512 + k0 + scol, Bs0 + row * 64 + scol);
    }
#pragma unroll
    for (int j = 0; j < 4; ++j) {
      int row = j * 32 + srow;
      GLOAD_LDS16(Wb + (size_t)(1024 + i0 + row) * 512 + k0 + scol, Bs1 + row * 64 + scol);
    }
    __syncthreads();   // compiler drains vmcnt before barrier -> LDS ready

#pragma unroll
    for (int kk = 0; kk < 2; ++kk) {
      const int kof = kk * 32 + (lane >> 4) * 8;
      const int rl = lane & 15;
      short8 av[4], b0[4], b1[4];
#pragma unroll
      for (int f = 0; f < 4; ++f)
        av[f] = *(const short8*)(As + (wm + f * 16 + rl) * 64 + kof);
#pragma unroll
      for (int g = 0; g < 4; ++g) {
        b0[g] = *(const short8*)(Bs0 + (wn + g * 16 + rl) * 64 + kof);
        b1[g] = *(const short8*)(Bs1 + (wn + g * 16 + rl) * 64 + kof);
      }
#pragma unroll
      for (int f = 0; f < 4; ++f)
#pragma unroll
        for (int g = 0; g < 4; ++g) {
          acc0[f][g] = __builtin_amdgcn_mfma_f32_16x16x32_bf16(av[f], b0[g], acc0[f][g], 0, 0, 0);
          acc1[f][g] = __builtin_amdgcn_mfma_f32_16x16x32_bf16(av[f], b1[g], acc1[f][g], 0, 0, 0);
        }
    }
  }

  // ---- fused epilogue: nonlinearity + packed store + chunk-aggregate ----
  // C/D layout: col = lane&15, row = (lane>>4)*4 + reg
  const int rl = lane & 15;
  const int q  = lane >> 4;
  const int mb = m0 + wm;             // wave row base == chunk base (CH=64)
  const int b  = mb >> 13;            // /8192
  const int c  = (mb & 8191) >> 6;    // /64

#pragma unroll
  for (int g = 0; g < 4; ++g) {
    const int i = i0 + wn + g * 16 + rl;
    float Achunk = 1.f, Vchunk = 0.f;
#pragma unroll
    for (int f = 0; f < 4; ++f) {
      float Aseg = 1.f, Vseg = 0.f;
#pragma unroll
      for (int r = 0; r < 4; ++r) {
        float h    = acc0[f][g][r];
        float gate = acc1[f][g][r];
        float e  = __expf(gate);
        float ac = __builtin_amdgcn_rcpf(1.f + e);   // sigmoid(-gate)
        float z  = e * ac;                           // sigmoid(gate)
        float gg;
        if (h >= 0.f) gg = h + 0.5f;
        else { float eh = __expf(h); gg = eh * __builtin_amdgcn_rcpf(1.f + eh); }
        float v = z * gg;
        int m = mb + f * 16 + q * 4 + r;
        avArr[(size_t)m * 1024 + i] = (uint32_t)f2bf(ac) | ((uint32_t)f2bf(v) << 16);
        // in-lane ordered fold over r (rows q*4+r ascending)
        Vseg = Vseg * ac + v;
        Aseg = Aseg * ac;
      }
      // ordered butterfly over q: step 16 (q^1), then step 32 (q^2)
      {
        float Ap = __shfl_xor(Aseg, 16);
        float Vp = __shfl_xor(Vseg, 16);
        if (q & 1) { Vseg = Vp * Aseg + Vseg; Aseg = Ap * Aseg; }
        else       { Vseg = Vseg * Ap + Vp;   Aseg = Aseg * Ap; }
      }
      {
        float Ap = __shfl_xor(Aseg, 32);
        float Vp = __shfl_xor(Vseg, 32);
        if (q & 2) { Vseg = Vp * Aseg + Vseg; Aseg = Ap * Aseg; }
        else       { Vseg = Vseg * Ap + Vp;   Aseg = Aseg * Ap; }
      }
      // sequential fold over f (rows f*16.. ascending)
      Vchunk = Vchunk * Aseg + Vseg;
      Achunk = Achunk * Aseg;
    }
    if (lane < 16) {
      size_t co = ((size_t)b * NC + c) * 1024 + i;
      Acar[co] = Achunk;
      Vcar[co] = Vchunk;
    }
  }
}

// ---------------- scan phase B: sequential carry combine over chunks ----------
__global__ void k_scanB(const float* __restrict__ hidden,
                        const float* __restrict__ Acar, const float* __restrict__ Vcar,
                        float* __restrict__ Hstart)
{
  int t = blockIdx.x * blockDim.x + threadIdx.x;  // 0..4095
  int b = t >> 10, i = t & 1023;
  float H = hidden[(size_t)b * 1024 + i];
  for (int c = 0; c < NC; ++c) {
    size_t o = ((size_t)b * NC + c) * 1024 + i;
    Hstart[o] = H;
    H = fmaf(Acar[o], H, Vcar[o]);
  }
}

// ---------------- fused scanC + GEMM2 ----------------------------------------
// One block == one scan chunk (64 seq rows) == one unique 64x512 output tile.
// Phase 1: scan the chunk (avArr 256KB + Hstart), H -> bf16 into XOR-swizzled
//          128KB LDS tile [64 rows x 1024 i].  (reg-staged write: swizzle is
//          write+read consistent, rule #21)
// Phase 2: out-tile = Htile @ W_out^T.  A from LDS (no barriers in K-loop:
//          LDS tile is read-only after the one barrier), B fragments straight
//          from global (Woutb = 1MB, L2-resident).
__global__ __launch_bounds__(512, 2) void k_scan_gemm2(
    const uint32_t* __restrict__ av,
    const float* __restrict__ Hstart,
    const unsigned short* __restrict__ Wout,   // 512 x 1024 bf16
    float* __restrict__ out,                   // 32768 x 512 f32
    float* __restrict__ nextH)                 // 4 x 1024 f32
{
  __shared__ unsigned short hs[64 * 1024];     // 128 KB

  const int chunk = blockIdx.x;        // 0..511
  const int b = chunk >> 7;            // /128
  const int c = chunk & 127;
  const int mb = b * 8192 + c * 64;    // first global row of this chunk
  const int tid = threadIdx.x;         // 0..511

  // ---- phase 1: scan 64 steps, 2 channels per thread ----
  {
    const int i2 = tid * 2;            // channel pair
    float2 H = reinterpret_cast<const float2*>(Hstart + ((size_t)(b * NC + c)) * 1024)[tid];
    const uint2* av2 = reinterpret_cast<const uint2*>(av) + (size_t)mb * 512 + tid;
#pragma unroll 4
    for (int t = 0; t < CH; ++t) {
      uint2 u = av2[(size_t)t * 512];
      H.x = fmaf(bf2f(u.x & 0xffffu), H.x, bf2f(u.x >> 16));
      H.y = fmaf(bf2f(u.y & 0xffffu), H.y, bf2f(u.y >> 16));
      uint32_t packed = (uint32_t)f2bf(H.x) | ((uint32_t)f2bf(H.y) << 16);
      int byte = (t * 2048 + i2 * 2) ^ ((t & 7) << 4);
      *reinterpret_cast<uint32_t*>(reinterpret_cast<char*>(hs) + byte) = packed;
    }
    if (c == NC - 1)
      reinterpret_cast<float2*>(nextH + (size_t)b * 1024)[tid] = H;
  }
  __syncthreads();

  // ---- phase 2: 64x512 GEMM, A from LDS, B from global ----
  const int lane = tid & 63;
  const int wave = tid >> 6;           // 0..7
  const int wm2 = (wave >> 2) * 32;    // m sub-range: 0 or 32 (2 m-frags)
  const int wn2 = (wave & 3) * 128;    // n sub-range: 0/128/256/384 (8 n-frags)
  const int rl = lane & 15;
  const int q  = lane >> 4;

  f32x4 acc[2][8];
#pragma unroll
  for (int f = 0; f < 2; ++f)
#pragma unroll
    for (int g = 0; g < 8; ++g) acc[f][g] = f32x4{0.f, 0.f, 0.f, 0.f};

  for (int kk = 0; kk < 32; ++kk) {    // K = 1024 in steps of 32
    const int kof = kk * 32 + q * 8;   // bf16 element offset in k
    short8 a[2], bv[8];
#pragma unroll
    for (int f = 0; f < 2; ++f) {
      int row = wm2 + f * 16 + rl;
      int byte = (row * 2048 + kof * 2) ^ ((row & 7) << 4);
      a[f] = *reinterpret_cast<const short8*>(reinterpret_cast<const char*>(hs) + byte);
    }
#pragma unroll
    for (int g = 0; g < 8; ++g) {
      int n = wn2 + g * 16 + rl;
      bv[g] = *reinterpret_cast<const short8*>(Wout + (size_t)n * 1024 + kof);
    }
#pragma unroll
    for (int f = 0; f < 2; ++f)
#pragma unroll
      for (int g = 0; g < 8; ++g)
        acc[f][g] = __builtin_amdgcn_mfma_f32_16x16x32_bf16(a[f], bv[g], acc[f][g], 0, 0, 0);
  }

  // C-write: col = lane&15 -> n, row = q*4+r -> m
#pragma unroll
  for (int f = 0; f < 2; ++f)
#pragma unroll
    for (int g = 0; g < 8; ++g)
#pragma unroll
      for (int r = 0; r < 4; ++r) {
        int m = mb + wm2 + f * 16 + q * 4 + r;
        int n = wn2 + g * 16 + rl;
        out[(size_t)m * 512 + n] = acc[f][g][r];
      }
}

// ---------------- driver ----------------
extern "C" void kernel_launch(void* const* d_in, const int* in_sizes, int n_in,
                              void* d_out, int out_size, void* d_ws, size_t ws_size,
                              hipStream_t stream) {
  const float* X      = (const float*)d_in[0];
  const float* hidden = (const float*)d_in[1];
  const float* W_hg   = (const float*)d_in[2];
  const float* W_out  = (const float*)d_in[3];

  float* out   = (float*)d_out;                    // (4,8192,512) f32
  float* nextH = out + (size_t)32768 * 512;        // (4,1,1024) f32

  char* ws = (char*)d_ws;
  size_t off = 0;
  auto alloc = [&](size_t bytes) -> void* {
    void* p = ws + off;
    off = (off + bytes + 255) & ~(size_t)255;
    return p;
  };
  unsigned short* Xb    = (unsigned short*)alloc(32768ULL * 512 * 2);
  unsigned short* Whgb  = (unsigned short*)alloc(2048ULL * 512 * 2);
  unsigned short* Woutb = (unsigned short*)alloc(512ULL * 1024 * 2);
  float*    Acar   = (float*)alloc(4ULL * NC * 1024 * 4);
  float*    Vcar   = (float*)alloc(4ULL * NC * 1024 * 4);
  float*    Hstart = (float*)alloc(4ULL * NC * 1024 * 4);
  uint32_t* avArr  = (uint32_t*)alloc(32768ULL * 1024 * 4);

  k_cvt_all<<<17920, 256, 0, stream>>>(X, W_hg, W_out, Xb, Whgb, Woutb);

  dim3 g1(8, 256);
  k_gemm1<<<g1, 256, 0, stream>>>(Xb, Whgb, avArr, Acar, Vcar);

  k_scanB<<<16, 256, 0, stream>>>(hidden, Acar, Vcar, Hstart);

  k_scan_gemm2<<<512, 512, 0, stream>>>(avArr, Hstart, Woutb, out, nextH);
}

// Round 9
// 316.226 us; speedup vs baseline: 1.2077x; 1.2077x over previous
//
#include <hip/hip_runtime.h>
#include <hip/hip_bf16.h>
#include <stdint.h>

typedef __attribute__((ext_vector_type(8))) short short8;
typedef __attribute__((ext_vector_type(4))) float f32x4;

#define CH 64
#define NC 128   /* 8192 / CH */

__device__ __forceinline__ unsigned short f2bf(float f) {
  union { float f; unsigned u; } x; x.f = f;
  unsigned u = x.u;
  u = (u + 0x7fffu + ((u >> 16) & 1u)) >> 16;
  return (unsigned short)u;
}
__device__ __forceinline__ float bf2f(unsigned u16) {
  union { unsigned u; float f; } x; x.u = u16 << 16;
  return x.f;
}

#define GLOAD_LDS16(gptr, lptr) \
  __builtin_amdgcn_global_load_lds((const __attribute__((address_space(1))) void*)(gptr), \
                                   (__attribute__((address_space(3))) void*)(lptr), 16, 0, 0)

// ---------------- fused f32 -> bf16 convert for X, W_hg, W_out ----------------
#define NQ_X   4194304  /* 16777216/4 */
#define NQ_WHG  262144  /* 1048576/4  */
#define NQ_WOUT 131072  /* 524288/4   */
__global__ void k_cvt_all(const float* __restrict__ X, const float* __restrict__ Whg,
                          const float* __restrict__ Wout,
                          unsigned short* __restrict__ Xb, unsigned short* __restrict__ Whgb,
                          unsigned short* __restrict__ Woutb) {
  int i = blockIdx.x * blockDim.x + threadIdx.x;  // 0 .. 4587519
  const float* src; unsigned short* dst; int off;
  if (i < NQ_X)                { src = X;    dst = Xb;    off = i; }
  else if (i < NQ_X + NQ_WHG)  { src = Whg;  dst = Whgb;  off = i - NQ_X; }
  else                         { src = Wout; dst = Woutb; off = i - NQ_X - NQ_WHG; }
  float4 f = reinterpret_cast<const float4*>(src)[off];
  ushort4 o = make_ushort4(f2bf(f.x), f2bf(f.y), f2bf(f.z), f2bf(f.w));
  reinterpret_cast<ushort4*>(dst)[off] = o;
}

// ---------------- GEMM1: hg = X @ W_hg^T, dual-B (h and gate halves) ---------
// Epilogue fuses the MinGRU nonlinearity, writes packed (a|v<<16) bf16 pairs,
// AND computes the per-chunk scan aggregates (scanA fused).
// NOTE: __launch_bounds__(256,2) is REQUIRED — acc0+acc1 = 128 regs must fit
// the unified VGPR+AGPR file. (256,3) caps at 170 and spills accumulators to
// scratch: measured +1.3 GB HBM traffic, MfmaUtil 21->7.7%, 2.7x slower (r6).
// Grid: 1D 2048 with chunked XCD swizzle — each XCD owns 32 consecutive
// m-tiles and iterates the 8 i-blocks per m-tile consecutively, so the A-tile
// stays L2-hot (reuse distance 8 blocks) and all 2 MB of B is L2-resident.
__global__ __launch_bounds__(256, 2) void k_gemm1(
    const unsigned short* __restrict__ Xb,
    const unsigned short* __restrict__ Wb,
    uint32_t* __restrict__ avArr,
    float* __restrict__ Acar, float* __restrict__ Vcar)
{
  __shared__ unsigned short As[128 * 64];
  __shared__ unsigned short Bs0[128 * 64];
  __shared__ unsigned short Bs1[128 * 64];

  const int bid  = blockIdx.x;         // 0..2047
  const int xcd  = bid & 7;
  const int loc  = bid >> 3;           // 0..255
  const int at   = loc >> 3;           // 0..31  A-tile within XCD
  const int yt   = loc & 7;            // 0..7   i-block
  const int m0 = (xcd * 32 + at) * 128;
  const int i0 = yt * 128;
  const int tid = threadIdx.x;
  const int lane = tid & 63;
  const int wave = tid >> 6;
  const int wm = (wave >> 1) * 64;
  const int wn = (wave & 1) * 64;
  const int srow = tid >> 3;         // 0..31
  const int scol = (tid & 7) * 8;    // element col in [0,64)

  f32x4 acc0[4][4], acc1[4][4];
#pragma unroll
  for (int f = 0; f < 4; ++f)
#pragma unroll
    for (int g = 0; g < 4; ++g) {
      acc0[f][g] = f32x4{0.f, 0.f, 0.f, 0.f};
      acc1[f][g] = f32x4{0.f, 0.f, 0.f, 0.f};
    }

  for (int k0 = 0; k0 < 512; k0 += 64) {
    __syncthreads();   // all waves done reading previous tile
#pragma unroll
    for (int j = 0; j < 4; ++j) {
      int row = j * 32 + srow;
      GLOAD_LDS16(Xb + (size_t)(m0 + row) * 512 + k0 + scol, As + row * 64 + scol);
    }
#pragma unroll
    for (int j = 0; j < 4; ++j) {
      int row = j * 32 + srow;
      GLOAD_LDS16(Wb + (size_t)(i0 + row) * 512 + k0 + scol, Bs0 + row * 64 + scol);
    }
#pragma unroll
    for (int j = 0; j < 4; ++j) {
      int row = j * 32 + srow;
      GLOAD_LDS16(Wb + (size_t)(1024 + i0 + row) * 512 + k0 + scol, Bs1 + row * 64 + scol);
    }
    __syncthreads();   // compiler drains vmcnt before barrier -> LDS ready

#pragma unroll
    for (int kk = 0; kk < 2; ++kk) {
      const int kof = kk * 32 + (lane >> 4) * 8;
      const int rl = lane & 15;
      short8 av[4], b0[4], b1[4];
#pragma unroll
      for (int f = 0; f < 4; ++f)
        av[f] = *(const short8*)(As + (wm + f * 16 + rl) * 64 + kof);
#pragma unroll
      for (int g = 0; g < 4; ++g) {
        b0[g] = *(const short8*)(Bs0 + (wn + g * 16 + rl) * 64 + kof);
        b1[g] = *(const short8*)(Bs1 + (wn + g * 16 + rl) * 64 + kof);
      }
#pragma unroll
      for (int f = 0; f < 4; ++f)
#pragma unroll
        for (int g = 0; g < 4; ++g) {
          acc0[f][g] = __builtin_amdgcn_mfma_f32_16x16x32_bf16(av[f], b0[g], acc0[f][g], 0, 0, 0);
          acc1[f][g] = __builtin_amdgcn_mfma_f32_16x16x32_bf16(av[f], b1[g], acc1[f][g], 0, 0, 0);
        }
    }
  }

  // ---- fused epilogue: nonlinearity + packed store + chunk-aggregate ----
  // C/D layout: col = lane&15, row = (lane>>4)*4 + reg
  const int rl = lane & 15;
  const int q  = lane >> 4;
  const int mb = m0 + wm;             // wave row base == chunk base (CH=64)
  const int b  = mb >> 13;            // /8192
  const int c  = (mb & 8191) >> 6;    // /64

#pragma unroll
  for (int g = 0; g < 4; ++g) {
    const int i = i0 + wn + g * 16 + rl;
    float Achunk = 1.f, Vchunk = 0.f;
#pragma unroll
    for (int f = 0; f < 4; ++f) {
      float Aseg = 1.f, Vseg = 0.f;
#pragma unroll
      for (int r = 0; r < 4; ++r) {
        float h    = acc0[f][g][r];
        float gate = acc1[f][g][r];
        float e  = __expf(gate);
        float ac = __builtin_amdgcn_rcpf(1.f + e);   // sigmoid(-gate)
        float z  = e * ac;                           // sigmoid(gate)
        float gg;
        if (h >= 0.f) gg = h + 0.5f;
        else { float eh = __expf(h); gg = eh * __builtin_amdgcn_rcpf(1.f + eh); }
        float v = z * gg;
        int m = mb + f * 16 + q * 4 + r;
        avArr[(size_t)m * 1024 + i] = (uint32_t)f2bf(ac) | ((uint32_t)f2bf(v) << 16);
        // in-lane ordered fold over r (rows q*4+r ascending)
        Vseg = Vseg * ac + v;
        Aseg = Aseg * ac;
      }
      // ordered butterfly over q: step 16 (q^1), then step 32 (q^2)
      {
        float Ap = __shfl_xor(Aseg, 16);
        float Vp = __shfl_xor(Vseg, 16);
        if (q & 1) { Vseg = Vp * Aseg + Vseg; Aseg = Ap * Aseg; }
        else       { Vseg = Vseg * Ap + Vp;   Aseg = Aseg * Ap; }
      }
      {
        float Ap = __shfl_xor(Aseg, 32);
        float Vp = __shfl_xor(Vseg, 32);
        if (q & 2) { Vseg = Vp * Aseg + Vseg; Aseg = Ap * Aseg; }
        else       { Vseg = Vseg * Ap + Vp;   Aseg = Aseg * Ap; }
      }
      // sequential fold over f (rows f*16.. ascending)
      Vchunk = Vchunk * Aseg + Vseg;
      Achunk = Achunk * Aseg;
    }
    if (lane < 16) {
      size_t co = ((size_t)b * NC + c) * 1024 + i;
      Acar[co] = Achunk;
      Vcar[co] = Vchunk;
    }
  }
}

// ---------------- scan phase B: sequential carry combine over chunks ----------
__global__ void k_scanB(const float* __restrict__ hidden,
                        const float* __restrict__ Acar, const float* __restrict__ Vcar,
                        float* __restrict__ Hstart)
{
  int t = blockIdx.x * blockDim.x + threadIdx.x;  // 0..4095
  int b = t >> 10, i = t & 1023;
  float H = hidden[(size_t)b * 1024 + i];
  for (int c = 0; c < NC; ++c) {
    size_t o = ((size_t)b * NC + c) * 1024 + i;
    Hstart[o] = H;
    H = fmaf(Acar[o], H, Vcar[o]);
  }
}

// ---------------- scan phase C: re-scan with correct H, emit h_all (bf16) -----
__global__ void k_scanC(const uint32_t* __restrict__ av,
                        const float* __restrict__ Hstart,
                        unsigned short* __restrict__ hAll, float* __restrict__ nextH)
{
  int c = blockIdx.x & (NC - 1);
  int b = blockIdx.x >> 7;  // NC=128
  size_t base4 = (((size_t)b * 8192 + (size_t)c * CH) * 1024) / 4 + threadIdx.x;
  size_t ho = (((size_t)b * NC + c) * 1024) / 4 + threadIdx.x;
  float4 H = reinterpret_cast<const float4*>(Hstart)[ho];
#pragma unroll 4
  for (int t = 0; t < CH; ++t) {
    uint4 u = reinterpret_cast<const uint4*>(av)[base4 + (size_t)t * 256];
    H.x = fmaf(bf2f(u.x & 0xffffu), H.x, bf2f(u.x >> 16));
    H.y = fmaf(bf2f(u.y & 0xffffu), H.y, bf2f(u.y >> 16));
    H.z = fmaf(bf2f(u.z & 0xffffu), H.z, bf2f(u.z >> 16));
    H.w = fmaf(bf2f(u.w & 0xffffu), H.w, bf2f(u.w >> 16));
    ushort4 o = make_ushort4(f2bf(H.x), f2bf(H.y), f2bf(H.z), f2bf(H.w));
    reinterpret_cast<ushort4*>(hAll)[base4 + (size_t)t * 256] = o;
  }
  if (c == NC - 1)
    reinterpret_cast<float4*>(nextH)[(size_t)b * 256 + threadIdx.x] = H;
}

// ---------------- GEMM2: out = h_all @ W_out^T ----------------
__global__ __launch_bounds__(256, 2) void k_gemm2(
    const unsigned short* __restrict__ Ab,   // 32768 x 1024 bf16
    const unsigned short* __restrict__ Bb,   // 512 x 1024 bf16
    float* __restrict__ out)                 // 32768 x 512 f32
{
  __shared__ unsigned short As[128 * 64];
  __shared__ unsigned short Bs[128 * 64];

  const int m0 = blockIdx.y * 128;
  const int n0 = blockIdx.x * 128;
  const int tid = threadIdx.x;
  const int lane = tid & 63;
  const int wave = tid >> 6;
  const int wm = (wave >> 1) * 64;
  const int wn = (wave & 1) * 64;
  const int srow = tid >> 3;
  const int scol = (tid & 7) * 8;

  f32x4 acc[4][4];
#pragma unroll
  for (int f = 0; f < 4; ++f)
#pragma unroll
    for (int g = 0; g < 4; ++g) acc[f][g] = f32x4{0.f, 0.f, 0.f, 0.f};

  for (int k0 = 0; k0 < 1024; k0 += 64) {
    __syncthreads();
#pragma unroll
    for (int j = 0; j < 4; ++j) {
      int row = j * 32 + srow;
      GLOAD_LDS16(Ab + (size_t)(m0 + row) * 1024 + k0 + scol, As + row * 64 + scol);
    }
#pragma unroll
    for (int j = 0; j < 4; ++j) {
      int row = j * 32 + srow;
      GLOAD_LDS16(Bb + (size_t)(n0 + row) * 1024 + k0 + scol, Bs + row * 64 + scol);
    }
    __syncthreads();

#pragma unroll
    for (int kk = 0; kk < 2; ++kk) {
      const int kof = kk * 32 + (lane >> 4) * 8;
      const int rl = lane & 15;
      short8 av[4], bv[4];
#pragma unroll
      for (int f = 0; f < 4; ++f)
        av[f] = *(const short8*)(As + (wm + f * 16 + rl) * 64 + kof);
#pragma unroll
      for (int g = 0; g < 4; ++g)
        bv[g] = *(const short8*)(Bs + (wn + g * 16 + rl) * 64 + kof);
#pragma unroll
      for (int f = 0; f < 4; ++f)
#pragma unroll
        for (int g = 0; g < 4; ++g)
          acc[f][g] = __builtin_amdgcn_mfma_f32_16x16x32_bf16(av[f], bv[g], acc[f][g], 0, 0, 0);
    }
  }

  const int rl = lane & 15;
  const int rr = (lane >> 4) * 4;
#pragma unroll
  for (int f = 0; f < 4; ++f)
#pragma unroll
    for (int g = 0; g < 4; ++g)
#pragma unroll
      for (int r = 0; r < 4; ++r) {
        int m = m0 + wm + f * 16 + rr + r;
        int n = n0 + wn + g * 16 + rl;
        out[(size_t)m * 512 + n] = acc[f][g][r];
      }
}

// ---------------- driver ----------------
extern "C" void kernel_launch(void* const* d_in, const int* in_sizes, int n_in,
                              void* d_out, int out_size, void* d_ws, size_t ws_size,
                              hipStream_t stream) {
  const float* X      = (const float*)d_in[0];
  const float* hidden = (const float*)d_in[1];
  const float* W_hg   = (const float*)d_in[2];
  const float* W_out  = (const float*)d_in[3];

  float* out   = (float*)d_out;                    // (4,8192,512) f32
  float* nextH = out + (size_t)32768 * 512;        // (4,1,1024) f32

  char* ws = (char*)d_ws;
  size_t off = 0;
  auto alloc = [&](size_t bytes) -> void* {
    void* p = ws + off;
    off = (off + bytes + 255) & ~(size_t)255;
    return p;
  };
  unsigned short* Xb    = (unsigned short*)alloc(32768ULL * 512 * 2);
  unsigned short* Whgb  = (unsigned short*)alloc(2048ULL * 512 * 2);
  unsigned short* Woutb = (unsigned short*)alloc(512ULL * 1024 * 2);
  unsigned short* hAll  = (unsigned short*)alloc(32768ULL * 1024 * 2);
  float*    Acar   = (float*)alloc(4ULL * NC * 1024 * 4);
  float*    Vcar   = (float*)alloc(4ULL * NC * 1024 * 4);
  float*    Hstart = (float*)alloc(4ULL * NC * 1024 * 4);
  uint32_t* avArr  = (uint32_t*)alloc(32768ULL * 1024 * 4);

  k_cvt_all<<<17920, 256, 0, stream>>>(X, W_hg, W_out, Xb, Whgb, Woutb);

  k_gemm1<<<2048, 256, 0, stream>>>(Xb, Whgb, avArr, Acar, Vcar);

  k_scanB<<<16, 256, 0, stream>>>(hidden, Acar, Vcar, Hstart);
  k_scanC<<<512, 256, 0, stream>>>(avArr, Hstart, hAll, nextH);

  dim3 g2(4, 256);
  k_gemm2<<<g2, 256, 0, stream>>>(hAll, Woutb, out);
}

// Round 14
// 302.938 us; speedup vs baseline: 1.2607x; 1.0439x over previous
//
#include <hip/hip_runtime.h>
#include <hip/hip_bf16.h>
#include <stdint.h>

typedef __attribute__((ext_vector_type(8))) short short8;
typedef __attribute__((ext_vector_type(4))) float f32x4;

#define CH 64
#define NC 128   /* 8192 / CH */

__device__ __forceinline__ unsigned short f2bf(float f) {
  union { float f; unsigned u; } x; x.f = f;
  unsigned u = x.u;
  u = (u + 0x7fffu + ((u >> 16) & 1u)) >> 16;
  return (unsigned short)u;
}
__device__ __forceinline__ float bf2f(unsigned u16) {
  union { unsigned u; float f; } x; x.u = u16 << 16;
  return x.f;
}

#define GLOAD_LDS16(gptr, lptr) \
  __builtin_amdgcn_global_load_lds((const __attribute__((address_space(1))) void*)(gptr), \
                                   (__attribute__((address_space(3))) void*)(lptr), 16, 0, 0)

// ---------------- fused f32 -> bf16 convert for X, W_hg, W_out ----------------
#define NQ_X   4194304  /* 16777216/4 */
#define NQ_WHG  262144  /* 1048576/4  */
#define NQ_WOUT 131072  /* 524288/4   */
__global__ void k_cvt_all(const float* __restrict__ X, const float* __restrict__ Whg,
                          const float* __restrict__ Wout,
                          unsigned short* __restrict__ Xb, unsigned short* __restrict__ Whgb,
                          unsigned short* __restrict__ Woutb) {
  int i = blockIdx.x * blockDim.x + threadIdx.x;  // 0 .. 4587519
  const float* src; unsigned short* dst; int off;
  if (i < NQ_X)                { src = X;    dst = Xb;    off = i; }
  else if (i < NQ_X + NQ_WHG)  { src = Whg;  dst = Whgb;  off = i - NQ_X; }
  else                         { src = Wout; dst = Woutb; off = i - NQ_X - NQ_WHG; }
  float4 f = reinterpret_cast<const float4*>(src)[off];
  ushort4 o = make_ushort4(f2bf(f.x), f2bf(f.y), f2bf(f.z), f2bf(f.w));
  reinterpret_cast<ushort4*>(dst)[off] = o;
}

// ---------------- GEMM1: hg = X @ W_hg^T, dual-B (h and gate halves) ---------
// 3-buffer depth-2 software pipeline (T3/T4-minimum): BK=32, iteration t
// stages tile t+2 via global_load_lds, computes tile t%3, then counted
// s_waitcnt vmcnt(6) + raw s_barrier (never vmcnt(0) mid-loop) so the next
// tile's loads stay in flight across the barrier.
// Epilogue fuses the MinGRU nonlinearity, packed (a|v<<16) store, and the
// per-chunk scan aggregates (scanA).
// NOTE: __launch_bounds__(256,2) REQUIRED — acc0+acc1 = 128 regs; (256,3)
// caps at 170 and spills accumulators (r6: +1.3GB HBM, 2.7x slower).
// Grid: 1D 2048 chunked XCD swizzle (r9: FETCH 135->49MB).
#define TILE_ELEMS 12288   /* 3 arrays x 128 rows x 32 cols bf16 = 24KB */
__global__ __launch_bounds__(256, 2) void k_gemm1(
    const unsigned short* __restrict__ Xb,
    const unsigned short* __restrict__ Wb,
    uint32_t* __restrict__ avArr,
    float* __restrict__ Acar, float* __restrict__ Vcar)
{
  __shared__ unsigned short lds[3 * TILE_ELEMS];   // 72 KB: 3 bufs x (A|B0|B1)

  const int bid  = blockIdx.x;         // 0..2047
  const int xcd  = bid & 7;
  const int loc  = bid >> 3;           // 0..255
  const int at   = loc >> 3;           // 0..31  A-tile within XCD
  const int yt   = loc & 7;            // 0..7   i-block
  const int m0 = (xcd * 32 + at) * 128;
  const int i0 = yt * 128;
  const int tid = threadIdx.x;
  const int lane = tid & 63;
  const int wave = tid >> 6;
  const int wm = (wave >> 1) * 64;
  const int wn = (wave & 1) * 64;

  // staging geometry: 256 threads cover 64 rows x 32 cols per pass (16B each)
  const int srow2 = tid >> 2;          // 0..63
  const int sc8   = (tid & 3) * 8;     // bf16 col offset 0/8/16/24

  const unsigned short* gA  = Xb + (size_t)(m0 + srow2) * 512 + sc8;
  const unsigned short* gB0 = Wb + (size_t)(i0 + srow2) * 512 + sc8;
  const unsigned short* gB1 = Wb + (size_t)(1024 + i0 + srow2) * 512 + sc8;
  unsigned short* lA  = lds + srow2 * 32 + sc8;
  unsigned short* lB0 = lA + 4096;
  unsigned short* lB1 = lA + 8192;

#define STAGE(bi, t) do { \
    GLOAD_LDS16(gA  + (t) * 32,         lA  + (bi) * TILE_ELEMS); \
    GLOAD_LDS16(gA  + (t) * 32 + 32768, lA  + (bi) * TILE_ELEMS + 2048); \
    GLOAD_LDS16(gB0 + (t) * 32,         lB0 + (bi) * TILE_ELEMS); \
    GLOAD_LDS16(gB0 + (t) * 32 + 32768, lB0 + (bi) * TILE_ELEMS + 2048); \
    GLOAD_LDS16(gB1 + (t) * 32,         lB1 + (bi) * TILE_ELEMS); \
    GLOAD_LDS16(gB1 + (t) * 32 + 32768, lB1 + (bi) * TILE_ELEMS + 2048); \
  } while (0)

  f32x4 acc0[4][4], acc1[4][4];
#pragma unroll
  for (int f = 0; f < 4; ++f)
#pragma unroll
    for (int g = 0; g < 4; ++g) {
      acc0[f][g] = f32x4{0.f, 0.f, 0.f, 0.f};
      acc1[f][g] = f32x4{0.f, 0.f, 0.f, 0.f};
    }

  const int rl = lane & 15;
  const int q8 = (lane >> 4) * 8;
  const int aoff = (wm + rl) * 32 + q8;
  const int boff = (wn + rl) * 32 + q8;

  // prologue: stage tiles 0 and 1
  STAGE(0, 0);
  STAGE(1, 1);
  asm volatile("s_waitcnt vmcnt(6)" ::: "memory");   // tile 0 landed
  __builtin_amdgcn_s_barrier();
  __builtin_amdgcn_sched_barrier(0);

#pragma unroll
  for (int t = 0; t < 16; ++t) {               // K = 512 / BK = 32
    if (t + 2 < 16) STAGE((t + 2) % 3, t + 2);

    const unsigned short* bb = lds + (t % 3) * TILE_ELEMS;
    short8 av[4], b0[4], b1[4];
#pragma unroll
    for (int f = 0; f < 4; ++f)
      av[f] = *(const short8*)(bb + aoff + f * 512);
#pragma unroll
    for (int g = 0; g < 4; ++g) {
      b0[g] = *(const short8*)(bb + 4096 + boff + g * 512);
      b1[g] = *(const short8*)(bb + 8192 + boff + g * 512);
    }
#pragma unroll
    for (int f = 0; f < 4; ++f)
#pragma unroll
      for (int g = 0; g < 4; ++g) {
        acc0[f][g] = __builtin_amdgcn_mfma_f32_16x16x32_bf16(av[f], b0[g], acc0[f][g], 0, 0, 0);
        acc1[f][g] = __builtin_amdgcn_mfma_f32_16x16x32_bf16(av[f], b1[g], acc1[f][g], 0, 0, 0);
      }

    if (t < 15) {
      if (t + 2 < 16) { asm volatile("s_waitcnt vmcnt(6)" ::: "memory"); }
      else            { asm volatile("s_waitcnt vmcnt(0)" ::: "memory"); }
      __builtin_amdgcn_s_barrier();
      __builtin_amdgcn_sched_barrier(0);
    }
  }
#undef STAGE

  // ---- fused epilogue: nonlinearity + packed store + chunk-aggregate ----
  // C/D layout: col = lane&15, row = (lane>>4)*4 + reg
  const int q  = lane >> 4;
  const int mb = m0 + wm;             // wave row base == chunk base (CH=64)
  const int b  = mb >> 13;            // /8192
  const int c  = (mb & 8191) >> 6;    // /64

#pragma unroll
  for (int g = 0; g < 4; ++g) {
    const int i = i0 + wn + g * 16 + rl;
    float Achunk = 1.f, Vchunk = 0.f;
#pragma unroll
    for (int f = 0; f < 4; ++f) {
      float Aseg = 1.f, Vseg = 0.f;
#pragma unroll
      for (int r = 0; r < 4; ++r) {
        float h    = acc0[f][g][r];
        float gate = acc1[f][g][r];
        float e  = __expf(gate);
        float ac = __builtin_amdgcn_rcpf(1.f + e);   // sigmoid(-gate)
        float z  = e * ac;                           // sigmoid(gate)
        float gg;
        if (h >= 0.f) gg = h + 0.5f;
        else { float eh = __expf(h); gg = eh * __builtin_amdgcn_rcpf(1.f + eh); }
        float v = z * gg;
        int m = mb + f * 16 + q * 4 + r;
        avArr[(size_t)m * 1024 + i] = (uint32_t)f2bf(ac) | ((uint32_t)f2bf(v) << 16);
        // in-lane ordered fold over r (rows q*4+r ascending)
        Vseg = Vseg * ac + v;
        Aseg = Aseg * ac;
      }
      // ordered butterfly over q: step 16 (q^1), then step 32 (q^2)
      {
        float Ap = __shfl_xor(Aseg, 16);
        float Vp = __shfl_xor(Vseg, 16);
        if (q & 1) { Vseg = Vp * Aseg + Vseg; Aseg = Ap * Aseg; }
        else       { Vseg = Vseg * Ap + Vp;   Aseg = Aseg * Ap; }
      }
      {
        float Ap = __shfl_xor(Aseg, 32);
        float Vp = __shfl_xor(Vseg, 32);
        if (q & 2) { Vseg = Vp * Aseg + Vseg; Aseg = Ap * Aseg; }
        else       { Vseg = Vseg * Ap + Vp;   Aseg = Aseg * Ap; }
      }
      // sequential fold over f (rows f*16.. ascending)
      Vchunk = Vchunk * Aseg + Vseg;
      Achunk = Achunk * Aseg;
    }
    if (lane < 16) {
      size_t co = ((size_t)b * NC + c) * 1024 + i;
      Acar[co] = Achunk;
      Vcar[co] = Vchunk;
    }
  }
}

// ---------------- scan phase B: sequential carry combine over chunks ----------
__global__ void k_scanB(const float* __restrict__ hidden,
                        const float* __restrict__ Acar, const float* __restrict__ Vcar,
                        float* __restrict__ Hstart)
{
  int t = blockIdx.x * blockDim.x + threadIdx.x;  // 0..4095
  int b = t >> 10, i = t & 1023;
  float H = hidden[(size_t)b * 1024 + i];
  for (int c = 0; c < NC; ++c) {
    size_t o = ((size_t)b * NC + c) * 1024 + i;
    Hstart[o] = H;
    H = fmaf(Acar[o], H, Vcar[o]);
  }
}

// ---------------- scan phase C: re-scan with correct H, emit h_all (bf16) -----
__global__ void k_scanC(const uint32_t* __restrict__ av,
                        const float* __restrict__ Hstart,
                        unsigned short* __restrict__ hAll, float* __restrict__ nextH)
{
  int c = blockIdx.x & (NC - 1);
  int b = blockIdx.x >> 7;  // NC=128
  size_t base4 = (((size_t)b * 8192 + (size_t)c * CH) * 1024) / 4 + threadIdx.x;
  size_t ho = (((size_t)b * NC + c) * 1024) / 4 + threadIdx.x;
  float4 H = reinterpret_cast<const float4*>(Hstart)[ho];
#pragma unroll 4
  for (int t = 0; t < CH; ++t) {
    uint4 u = reinterpret_cast<const uint4*>(av)[base4 + (size_t)t * 256];
    H.x = fmaf(bf2f(u.x & 0xffffu), H.x, bf2f(u.x >> 16));
    H.y = fmaf(bf2f(u.y & 0xffffu), H.y, bf2f(u.y >> 16));
    H.z = fmaf(bf2f(u.z & 0xffffu), H.z, bf2f(u.z >> 16));
    H.w = fmaf(bf2f(u.w & 0xffffu), H.w, bf2f(u.w >> 16));
    ushort4 o = make_ushort4(f2bf(H.x), f2bf(H.y), f2bf(H.z), f2bf(H.w));
    reinterpret_cast<ushort4*>(hAll)[base4 + (size_t)t * 256] = o;
  }
  if (c == NC - 1)
    reinterpret_cast<float4*>(nextH)[(size_t)b * 256 + threadIdx.x] = H;
}

// ---------------- GEMM2: out = h_all @ W_out^T ----------------
__global__ __launch_bounds__(256, 2) void k_gemm2(
    const unsigned short* __restrict__ Ab,   // 32768 x 1024 bf16
    const unsigned short* __restrict__ Bb,   // 512 x 1024 bf16
    float* __restrict__ out)                 // 32768 x 512 f32
{
  __shared__ unsigned short As[128 * 64];
  __shared__ unsigned short Bs[128 * 64];

  const int m0 = blockIdx.y * 128;
  const int n0 = blockIdx.x * 128;
  const int tid = threadIdx.x;
  const int lane = tid & 63;
  const int wave = tid >> 6;
  const int wm = (wave >> 1) * 64;
  const int wn = (wave & 1) * 64;
  const int srow = tid >> 3;
  const int scol = (tid & 7) * 8;

  f32x4 acc[4][4];
#pragma unroll
  for (int f = 0; f < 4; ++f)
#pragma unroll
    for (int g = 0; g < 4; ++g) acc[f][g] = f32x4{0.f, 0.f, 0.f, 0.f};

  for (int k0 = 0; k0 < 1024; k0 += 64) {
    __syncthreads();
#pragma unroll
    for (int j = 0; j < 4; ++j) {
      int row = j * 32 + srow;
      GLOAD_LDS16(Ab + (size_t)(m0 + row) * 1024 + k0 + scol, As + row * 64 + scol);
    }
#pragma unroll
    for (int j = 0; j < 4; ++j) {
      int row = j * 32 + srow;
      GLOAD_LDS16(Bb + (size_t)(n0 + row) * 1024 + k0 + scol, Bs + row * 64 + scol);
    }
    __syncthreads();

#pragma unroll
    for (int kk = 0; kk < 2; ++kk) {
      const int kof = kk * 32 + (lane >> 4) * 8;
      const int rl = lane & 15;
      short8 av[4], bv[4];
#pragma unroll
      for (int f = 0; f < 4; ++f)
        av[f] = *(const short8*)(As + (wm + f * 16 + rl) * 64 + kof);
#pragma unroll
      for (int g = 0; g < 4; ++g)
        bv[g] = *(const short8*)(Bs + (wn + g * 16 + rl) * 64 + kof);
#pragma unroll
      for (int f = 0; f < 4; ++f)
#pragma unroll
        for (int g = 0; g < 4; ++g)
          acc[f][g] = __builtin_amdgcn_mfma_f32_16x16x32_bf16(av[f], bv[g], acc[f][g], 0, 0, 0);
    }
  }

  const int rl = lane & 15;
  const int rr = (lane >> 4) * 4;
#pragma unroll
  for (int f = 0; f < 4; ++f)
#pragma unroll
    for (int g = 0; g < 4; ++g)
#pragma unroll
      for (int r = 0; r < 4; ++r) {
        int m = m0 + wm + f * 16 + rr + r;
        int n = n0 + wn + g * 16 + rl;
        out[(size_t)m * 512 + n] = acc[f][g][r];
      }
}

// ---------------- driver ----------------
extern "C" void kernel_launch(void* const* d_in, const int* in_sizes, int n_in,
                              void* d_out, int out_size, void* d_ws, size_t ws_size,
                              hipStream_t stream) {
  const float* X      = (const float*)d_in[0];
  const float* hidden = (const float*)d_in[1];
  const float* W_hg   = (const float*)d_in[2];
  const float* W_out  = (const float*)d_in[3];

  float* out   = (float*)d_out;                    // (4,8192,512) f32
  float* nextH = out + (size_t)32768 * 512;        // (4,1,1024) f32

  char* ws = (char*)d_ws;
  size_t off = 0;
  auto alloc = [&](size_t bytes) -> void* {
    void* p = ws + off;
    off = (off + bytes + 255) & ~(size_t)255;
    return p;
  };
  unsigned short* Xb    = (unsigned short*)alloc(32768ULL * 512 * 2);
  unsigned short* Whgb  = (unsigned short*)alloc(2048ULL * 512 * 2);
  unsigned short* Woutb = (unsigned short*)alloc(512ULL * 1024 * 2);
  unsigned short* hAll  = (unsigned short*)alloc(32768ULL * 1024 * 2);
  float*    Acar   = (float*)alloc(4ULL * NC * 1024 * 4);
  float*    Vcar   = (float*)alloc(4ULL * NC * 1024 * 4);
  float*    Hstart = (float*)alloc(4ULL * NC * 1024 * 4);
  uint32_t* avArr  = (uint32_t*)alloc(32768ULL * 1024 * 4);

  k_cvt_all<<<17920, 256, 0, stream>>>(X, W_hg, W_out, Xb, Whgb, Woutb);

  k_gemm1<<<2048, 256, 0, stream>>>(Xb, Whgb, avArr, Acar, Vcar);

  k_scanB<<<16, 256, 0, stream>>>(hidden, Acar, Vcar, Hstart);
  k_scanC<<<512, 256, 0, stream>>>(avArr, Hstart, hAll, nextH);

  dim3 g2(4, 256);
  k_gemm2<<<g2, 256, 0, stream>>>(hAll, Woutb, out);
}